// Round 1
// baseline (870.845 us; speedup 1.0000x reference)
//
#include <hip/hip_runtime.h>
#include <math.h>

#define N_NODES 50000
#define N_EDGES 1600000
#define F 256
#define ALPHA 0.2f

// ---------- GEMM: Wh = X @ W + bias   (M=50000, K=256, N=256) fp32 ----------
__global__ __launch_bounds__(256) void gat_gemm(const float* __restrict__ X,
                                                const float* __restrict__ W,
                                                const float* __restrict__ bias,
                                                float* __restrict__ Wh) {
  __shared__ float As[64][68];  // [m][k], pad->68 so float4 rows stay 16B-aligned
  __shared__ float Bs[64][68];  // [k][n]
  const int tid = threadIdx.x;
  const int tx = tid & 15, ty = tid >> 4;
  const int m0 = blockIdx.x * 64;
  const int n0 = blockIdx.y * 64;
  float acc[4][4] = {};
  for (int k0 = 0; k0 < F; k0 += 64) {
#pragma unroll
    for (int j = 0; j < 4; ++j) {
      int q = tid + 256 * j;
      int r = q >> 4, c4 = q & 15;
      int gm = m0 + r;
      float4 v = make_float4(0.f, 0.f, 0.f, 0.f);
      if (gm < N_NODES) v = *(const float4*)(X + (size_t)gm * F + k0 + c4 * 4);
      *(float4*)&As[r][c4 * 4] = v;
      float4 w = *(const float4*)(W + (size_t)(k0 + r) * F + n0 + c4 * 4);
      *(float4*)&Bs[r][c4 * 4] = w;
    }
    __syncthreads();
#pragma unroll
    for (int kk = 0; kk < 64; kk += 4) {
      float4 b0 = *(float4*)&Bs[kk + 0][tx * 4];
      float4 b1 = *(float4*)&Bs[kk + 1][tx * 4];
      float4 b2 = *(float4*)&Bs[kk + 2][tx * 4];
      float4 b3 = *(float4*)&Bs[kk + 3][tx * 4];
#pragma unroll
      for (int i = 0; i < 4; ++i) {
        float4 av = *(float4*)&As[ty * 4 + i][kk];
        acc[i][0] += av.x * b0.x + av.y * b1.x + av.z * b2.x + av.w * b3.x;
        acc[i][1] += av.x * b0.y + av.y * b1.y + av.z * b2.y + av.w * b3.y;
        acc[i][2] += av.x * b0.z + av.y * b1.z + av.z * b2.z + av.w * b3.z;
        acc[i][3] += av.x * b0.w + av.y * b1.w + av.z * b2.w + av.w * b3.w;
      }
    }
    __syncthreads();
  }
  float4 bv = *(const float4*)(bias + n0 + tx * 4);
#pragma unroll
  for (int i = 0; i < 4; ++i) {
    int gm = m0 + ty * 4 + i;
    if (gm < N_NODES) {
      float4 o = make_float4(acc[i][0] + bv.x, acc[i][1] + bv.y,
                             acc[i][2] + bv.z, acc[i][3] + bv.w);
      *(float4*)(Wh + (size_t)gm * F + n0 + tx * 4) = o;
    }
  }
}

// ---------- per-node attention projections: f_dst = Wh.a1, f_row = Wh.a2 ----
__global__ __launch_bounds__(256) void gat_fvec(const float* __restrict__ Wh,
                                                const float* __restrict__ a_w,
                                                float* __restrict__ f_dst,
                                                float* __restrict__ f_row) {
  const int lane = threadIdx.x & 63;
  const int wid = threadIdx.x >> 6;
  const int node = blockIdx.x * 4 + wid;
  if (node >= N_NODES) return;
  float4 v = *(const float4*)(Wh + (size_t)node * F + lane * 4);
  float4 a1 = *(const float4*)(a_w + lane * 4);
  float4 a2 = *(const float4*)(a_w + F + lane * 4);
  float s1 = v.x * a1.x + v.y * a1.y + v.z * a1.z + v.w * a1.w;
  float s2 = v.x * a2.x + v.y * a2.y + v.z * a2.z + v.w * a2.w;
#pragma unroll
  for (int off = 32; off > 0; off >>= 1) {
    s1 += __shfl_down(s1, off, 64);
    s2 += __shfl_down(s2, off, 64);
  }
  if (lane == 0) { f_dst[node] = s1; f_row[node] = s2; }
}

// ---------- per-edge: e -> leaky -> exp; accumulate denom + degree ----------
// No max-subtraction: e ~ N(0,1), |e| <= ~6 over 1.6M samples -> exp safe in
// fp32; att = ex/denom identical to the max-shifted form.
__global__ __launch_bounds__(256) void gat_edge(const int* __restrict__ row,
                                                const int* __restrict__ col,
                                                const float* __restrict__ f_dst,
                                                const float* __restrict__ f_row,
                                                const float* __restrict__ a_b,
                                                float* __restrict__ exbuf,
                                                float* __restrict__ denom,
                                                int* __restrict__ deg) {
  int k = blockIdx.x * blockDim.x + threadIdx.x;
  if (k >= N_EDGES) return;
  int r = row[k], c = col[k];
  float e = f_dst[c] + f_row[r] + a_b[0];
  e = e > 0.f ? e : ALPHA * e;
  float ex = expf(e);
  exbuf[k] = ex;
  atomicAdd(&denom[r], ex);
  atomicAdd(&deg[r], 1);
}

// ---------- single-block exclusive scan over degrees -> row_start ----------
__global__ __launch_bounds__(1024) void gat_scan(const int* __restrict__ deg,
                                                 int* __restrict__ row_start,
                                                 int* __restrict__ cursor,
                                                 int n) {
  __shared__ int wsum[16];
  __shared__ int carry_s, tot_s;
  const int tid = threadIdx.x;
  const int lane = tid & 63, wid = tid >> 6;
  if (tid == 0) carry_s = 0;
  __syncthreads();
  for (int base = 0; base < n; base += 1024) {
    int idx = base + tid;
    int v = (idx < n) ? deg[idx] : 0;
    int incl = v;
#pragma unroll
    for (int off = 1; off < 64; off <<= 1) {
      int t = __shfl_up(incl, off, 64);
      if (lane >= off) incl += t;
    }
    if (lane == 63) wsum[wid] = incl;
    __syncthreads();
    if (tid == 0) {
      int run = 0;
#pragma unroll
      for (int i = 0; i < 16; ++i) { int t = wsum[i]; wsum[i] = run; run += t; }
      tot_s = run;
    }
    __syncthreads();
    int excl = carry_s + wsum[wid] + incl - v;
    if (idx < n) { row_start[idx] = excl; cursor[idx] = excl; }
    __syncthreads();
    if (tid == 0) carry_s += tot_s;
    __syncthreads();
  }
  if (tid == 0) row_start[n] = carry_s;
}

// ---------- CSR fill ----------
__global__ __launch_bounds__(256) void gat_fill(const int* __restrict__ row,
                                                const int* __restrict__ col,
                                                const float* __restrict__ exbuf,
                                                int* __restrict__ cursor,
                                                int* __restrict__ csr_col,
                                                float* __restrict__ csr_w) {
  int k = blockIdx.x * blockDim.x + threadIdx.x;
  if (k >= N_EDGES) return;
  int r = row[k];
  int p = atomicAdd(&cursor[r], 1);
  csr_col[p] = col[k];
  csr_w[p] = exbuf[k];
}

// ---------- pull-mode SpMM + normalize + ReLU: one wave per row ----------
__global__ __launch_bounds__(256) void gat_pull(const int* __restrict__ row_start,
                                                const int* __restrict__ csr_col,
                                                const float* __restrict__ csr_w,
                                                const float* __restrict__ denom,
                                                const float* __restrict__ Wh,
                                                float* __restrict__ out) {
  const int lane = threadIdx.x & 63;
  const int wid = threadIdx.x >> 6;
  const int i = blockIdx.x * 4 + wid;
  if (i >= N_NODES) return;
  const int s = row_start[i], e = row_start[i + 1];
  const float4* Wh4 = (const float4*)Wh;
  float4 acc = make_float4(0.f, 0.f, 0.f, 0.f);
  for (int p = s; p < e; ++p) {
    int c = csr_col[p];
    float w = csr_w[p];
    float4 v = Wh4[(size_t)c * 64 + lane];
    acc.x += w * v.x; acc.y += w * v.y; acc.z += w * v.z; acc.w += w * v.w;
  }
  if (e > s) {
    float inv = 1.0f / denom[i];
    acc.x *= inv; acc.y *= inv; acc.z *= inv; acc.w *= inv;
  }
  acc.x = fmaxf(acc.x, 0.f); acc.y = fmaxf(acc.y, 0.f);
  acc.z = fmaxf(acc.z, 0.f); acc.w = fmaxf(acc.w, 0.f);
  ((float4*)out)[(size_t)i * 64 + lane] = acc;
}

extern "C" void kernel_launch(void* const* d_in, const int* in_sizes, int n_in,
                              void* d_out, int out_size, void* d_ws, size_t ws_size,
                              hipStream_t stream) {
  const float* x   = (const float*)d_in[0];
  const float* W_w = (const float*)d_in[1];
  const float* W_b = (const float*)d_in[2];
  const float* a_w = (const float*)d_in[3];
  const float* a_b = (const float*)d_in[4];
  const int*   row = (const int*)d_in[5];
  const int*   col = (const int*)d_in[6];
  float* out = (float*)d_out;

  // workspace layout (floats; ~71.6 MB total)
  const size_t NP = 50048;  // padded N
  float* ws = (float*)d_ws;
  size_t off = 0;
  float* Wh        = ws + off; off += (size_t)N_NODES * F;  // 12.8M
  float* f_dst     = ws + off; off += NP;
  float* f_row     = ws + off; off += NP;
  float* denom     = ws + off; off += NP;   // memset 0 (contiguous with deg)
  int*   deg       = (int*)(ws + off); off += NP;
  int*   row_start = (int*)(ws + off); off += NP;  // N+1 fits
  int*   cursor    = (int*)(ws + off); off += NP;
  float* exbuf     = ws + off; off += N_EDGES;
  int*   csr_col   = (int*)(ws + off); off += N_EDGES;
  float* csr_w     = ws + off; off += N_EDGES;
  (void)ws_size; (void)in_sizes; (void)n_in; (void)out_size;

  // ws is poisoned 0xAA before every timed launch: zero denom+deg ourselves.
  hipMemsetAsync(denom, 0, 2 * NP * sizeof(float), stream);

  hipLaunchKernelGGL(gat_gemm, dim3((N_NODES + 63) / 64, F / 64), dim3(256), 0,
                     stream, x, W_w, W_b, Wh);
  hipLaunchKernelGGL(gat_fvec, dim3((N_NODES + 3) / 4), dim3(256), 0, stream,
                     Wh, a_w, f_dst, f_row);
  hipLaunchKernelGGL(gat_edge, dim3((N_EDGES + 255) / 256), dim3(256), 0,
                     stream, row, col, f_dst, f_row, a_b, exbuf, denom, deg);
  hipLaunchKernelGGL(gat_scan, dim3(1), dim3(1024), 0, stream, deg, row_start,
                     cursor, N_NODES);
  hipLaunchKernelGGL(gat_fill, dim3((N_EDGES + 255) / 256), dim3(256), 0,
                     stream, row, col, exbuf, cursor, csr_col, csr_w);
  hipLaunchKernelGGL(gat_pull, dim3((N_NODES + 3) / 4), dim3(256), 0, stream,
                     row_start, csr_col, csr_w, denom, Wh, out);
}

// Round 2
// 551.835 us; speedup vs baseline: 1.5781x; 1.5781x over previous
//
#include <hip/hip_runtime.h>
#include <math.h>

#define N_NODES 50000
#define N_EDGES 1600000
#define F 256
#define ALPHA 0.2f
#define NP 50048  // padded node count (multiple of 128)

typedef short bf16x8 __attribute__((ext_vector_type(8)));
typedef float f32x4 __attribute__((ext_vector_type(4)));

__device__ __forceinline__ unsigned short f2bf(float f) {
  union { float f; unsigned u; } v; v.f = f;
  unsigned u = v.u;
  return (unsigned short)((u + 0x7fffu + ((u >> 16) & 1u)) >> 16);
}

// ---- prep_w: W (256x256 fp32) -> Wt bf16 transposed [n][k]; wa1/wa2 = W @ a_halves
__global__ __launch_bounds__(256) void prep_w(const float* __restrict__ W,
                                              const float* __restrict__ a_w,
                                              unsigned short* __restrict__ Wt,
                                              float* __restrict__ wa) {
  const int lane = threadIdx.x & 63, w = threadIdx.x >> 6;
  const int k = blockIdx.x * 4 + w;  // 0..255
  float4 wv = *(const float4*)(W + (size_t)k * F + lane * 4);
  float4 a1 = *(const float4*)(a_w + lane * 4);
  float4 a2 = *(const float4*)(a_w + F + lane * 4);
  // transposed bf16 store: Wt[n*256 + k] = W[k][n]
  Wt[(size_t)(lane * 4 + 0) * F + k] = f2bf(wv.x);
  Wt[(size_t)(lane * 4 + 1) * F + k] = f2bf(wv.y);
  Wt[(size_t)(lane * 4 + 2) * F + k] = f2bf(wv.z);
  Wt[(size_t)(lane * 4 + 3) * F + k] = f2bf(wv.w);
  float s1 = wv.x * a1.x + wv.y * a1.y + wv.z * a1.z + wv.w * a1.w;
  float s2 = wv.x * a2.x + wv.y * a2.y + wv.z * a2.z + wv.w * a2.w;
#pragma unroll
  for (int off = 32; off > 0; off >>= 1) {
    s1 += __shfl_down(s1, off, 64);
    s2 += __shfl_down(s2, off, 64);
  }
  if (lane == 0) { wa[k] = s1; wa[F + k] = s2; }
}

// ---- prep_scalars: cb[0] = W_b.a1 ; cb[1] = W_b.a2 + a_b (fold all constants)
__global__ __launch_bounds__(64) void prep_scalars(const float* __restrict__ W_b,
                                                   const float* __restrict__ a_w,
                                                   const float* __restrict__ a_b,
                                                   float* __restrict__ cb) {
  const int l = threadIdx.x;
  float4 b = *(const float4*)(W_b + l * 4);
  float4 a1 = *(const float4*)(a_w + l * 4);
  float4 a2 = *(const float4*)(a_w + F + l * 4);
  float s1 = b.x * a1.x + b.y * a1.y + b.z * a1.z + b.w * a1.w;
  float s2 = b.x * a2.x + b.y * a2.y + b.z * a2.z + b.w * a2.w;
#pragma unroll
  for (int off = 32; off > 0; off >>= 1) {
    s1 += __shfl_down(s1, off, 64);
    s2 += __shfl_down(s2, off, 64);
  }
  if (l == 0) { cb[0] = s1; cb[1] = s2 + a_b[0]; }
}

// ---- fvec2: exact fp32 attention projections straight from x: f = x . wa + cb
__global__ __launch_bounds__(256) void fvec2(const float* __restrict__ x,
                                             const float* __restrict__ wa,
                                             const float* __restrict__ cb,
                                             float* __restrict__ f_dst,
                                             float* __restrict__ f_row) {
  const int lane = threadIdx.x & 63, w = threadIdx.x >> 6;
  const int node = blockIdx.x * 4 + w;
  if (node >= N_NODES) return;
  float4 xv = *(const float4*)(x + (size_t)node * F + lane * 4);
  float4 v1 = *(const float4*)(wa + lane * 4);
  float4 v2 = *(const float4*)(wa + F + lane * 4);
  float s1 = xv.x * v1.x + xv.y * v1.y + xv.z * v1.z + xv.w * v1.w;
  float s2 = xv.x * v2.x + xv.y * v2.y + xv.z * v2.z + xv.w * v2.w;
#pragma unroll
  for (int off = 32; off > 0; off >>= 1) {
    s1 += __shfl_down(s1, off, 64);
    s2 += __shfl_down(s2, off, 64);
  }
  if (lane == 0) { f_dst[node] = s1 + cb[0]; f_row[node] = s2 + cb[1]; }
}

// ---- MFMA GEMM: Wh = x @ W + bias, bf16 inputs, fp32 accumulate.
// 128x128 tile, BK=64, 4 waves of 64x64 each, 16x16x32 bf16 MFMA.
#define LDSK 72  // padded row stride (bf16 elems) to spread LDS banks
__global__ __launch_bounds__(256) void gemm_mfma(const float* __restrict__ X,
                                                 const unsigned short* __restrict__ Wt,
                                                 const float* __restrict__ bias,
                                                 float* __restrict__ Wh) {
  __shared__ short As[128 * LDSK];
  __shared__ short Bs[128 * LDSK];
  const int tid = threadIdx.x;
  const int lane = tid & 63;
  const int w = tid >> 6;
  const int wm = w >> 1, wn = w & 1;
  const int m0 = blockIdx.x * 128;
  const int n0 = blockIdx.y * 128;
  f32x4 acc[4][4] = {{{0.f, 0.f, 0.f, 0.f}}};
  const int srow = tid >> 3;   // 0..31
  const int schunk = tid & 7;  // 0..7

  for (int k0 = 0; k0 < F; k0 += 64) {
#pragma unroll
    for (int i = 0; i < 4; ++i) {
      int r = i * 32 + srow;
      int gm = m0 + r; if (gm > N_NODES - 1) gm = N_NODES - 1;  // clamp (pad rows)
      const float* src = X + (size_t)gm * F + k0 + schunk * 8;
      float4 lo = *(const float4*)src;
      float4 hi = *(const float4*)(src + 4);
      bf16x8 v;
      v[0] = (short)f2bf(lo.x); v[1] = (short)f2bf(lo.y);
      v[2] = (short)f2bf(lo.z); v[3] = (short)f2bf(lo.w);
      v[4] = (short)f2bf(hi.x); v[5] = (short)f2bf(hi.y);
      v[6] = (short)f2bf(hi.z); v[7] = (short)f2bf(hi.w);
      *(bf16x8*)&As[r * LDSK + schunk * 8] = v;
      const unsigned short* bsrc = Wt + (size_t)(n0 + r) * F + k0 + schunk * 8;
      *(bf16x8*)&Bs[r * LDSK + schunk * 8] = *(const bf16x8*)bsrc;
    }
    __syncthreads();
#pragma unroll
    for (int kk = 0; kk < 64; kk += 32) {
      const int rowsel = lane & 15;
      const int ksel = kk + (lane >> 4) * 8;
      bf16x8 af[4], bfr[4];
#pragma unroll
      for (int t = 0; t < 4; ++t) {
        af[t] = *(bf16x8*)&As[(wm * 64 + t * 16 + rowsel) * LDSK + ksel];
        bfr[t] = *(bf16x8*)&Bs[(wn * 64 + t * 16 + rowsel) * LDSK + ksel];
      }
#pragma unroll
      for (int mi = 0; mi < 4; ++mi)
#pragma unroll
        for (int nj = 0; nj < 4; ++nj)
          acc[mi][nj] = __builtin_amdgcn_mfma_f32_16x16x32_bf16(
              af[mi], bfr[nj], acc[mi][nj], 0, 0, 0);
    }
    __syncthreads();
  }
  // epilogue: C/D layout col=lane&15, row=(lane>>4)*4+reg
  const int crow = (lane >> 4) * 4;
  const int ccol = lane & 15;
#pragma unroll
  for (int nj = 0; nj < 4; ++nj) {
    int gc = n0 + wn * 64 + nj * 16 + ccol;
    float bv = bias[gc];
#pragma unroll
    for (int mi = 0; mi < 4; ++mi) {
      int gr = m0 + wm * 64 + mi * 16 + crow;
#pragma unroll
      for (int r = 0; r < 4; ++r)
        Wh[(size_t)(gr + r) * F + gc] = acc[mi][nj][r] + bv;  // padded rows OK
    }
  }
}

// ---- degree count
__global__ __launch_bounds__(256) void deg_count(const int* __restrict__ row,
                                                 int* __restrict__ deg) {
  int k = blockIdx.x * 256 + threadIdx.x;
  if (k < N_EDGES) atomicAdd(&deg[row[k]], 1);
}

// ---- hierarchical exclusive scan (3 kernels)
__global__ __launch_bounds__(256) void scan1(const int* __restrict__ deg,
                                             int* __restrict__ part,
                                             int* __restrict__ bsum) {
  __shared__ int wsum[4];
  const int tid = threadIdx.x, lane = tid & 63, w = tid >> 6;
  const int idx = blockIdx.x * 256 + tid;
  int v = (idx < N_NODES) ? deg[idx] : 0;
  int incl = v;
#pragma unroll
  for (int off = 1; off < 64; off <<= 1) {
    int t = __shfl_up(incl, off, 64);
    if (lane >= off) incl += t;
  }
  if (lane == 63) wsum[w] = incl;
  __syncthreads();
  int prev = 0;
#pragma unroll
  for (int i = 0; i < 4; ++i) if (i < w) prev += wsum[i];
  if (idx < N_NODES) part[idx] = prev + incl - v;
  if (tid == 255) bsum[blockIdx.x] = prev + incl;
}

__global__ __launch_bounds__(256) void scan2(const int* __restrict__ bsum,
                                             int* __restrict__ boffs, int nblk) {
  __shared__ int wsum[4];
  const int tid = threadIdx.x, lane = tid & 63, w = tid >> 6;
  int v = (tid < nblk) ? bsum[tid] : 0;
  int incl = v;
#pragma unroll
  for (int off = 1; off < 64; off <<= 1) {
    int t = __shfl_up(incl, off, 64);
    if (lane >= off) incl += t;
  }
  if (lane == 63) wsum[w] = incl;
  __syncthreads();
  int prev = 0;
#pragma unroll
  for (int i = 0; i < 4; ++i) if (i < w) prev += wsum[i];
  if (tid < nblk) boffs[tid] = prev + incl - v;
}

__global__ __launch_bounds__(256) void scan3(const int* __restrict__ part,
                                             const int* __restrict__ boffs,
                                             int* __restrict__ row_start,
                                             int* __restrict__ cursor) {
  int idx = blockIdx.x * 256 + threadIdx.x;
  if (idx < N_NODES) {
    int rs = part[idx] + boffs[blockIdx.x];
    row_start[idx] = rs;
    cursor[idx] = rs;
  }
  if (idx == 0) row_start[N_NODES] = N_EDGES;
}

// ---- CSR fill (col only)
__global__ __launch_bounds__(256) void fill_csr(const int* __restrict__ row,
                                                const int* __restrict__ col,
                                                int* __restrict__ cursor,
                                                int* __restrict__ csr_col) {
  int k = blockIdx.x * 256 + threadIdx.x;
  if (k >= N_EDGES) return;
  int p = atomicAdd(&cursor[row[k]], 1);
  csr_col[p] = col[k];
}

// ---- pull: recompute attention, accumulate, normalize, ReLU. One wave/row.
__global__ __launch_bounds__(256) void gat_pull(const int* __restrict__ row_start,
                                                const int* __restrict__ csr_col,
                                                const float* __restrict__ f_dst,
                                                const float* __restrict__ f_row,
                                                const float* __restrict__ Wh,
                                                float* __restrict__ out) {
  const int lane = threadIdx.x & 63, w = threadIdx.x >> 6;
  const int i = blockIdx.x * 4 + w;
  if (i >= N_NODES) return;
  const int s = row_start[i], e = row_start[i + 1];
  const float fr = f_row[i];
  const float4* Wh4 = (const float4*)Wh;
  float4 acc = make_float4(0.f, 0.f, 0.f, 0.f);
  float sum = 0.f;
  for (int p = s; p < e; ++p) {
    int c = csr_col[p];               // wave-uniform -> broadcast load
    float ev = f_dst[c] + fr;
    ev = ev > 0.f ? ev : ALPHA * ev;
    float ex = __expf(ev);
    float4 v = Wh4[(size_t)c * 64 + lane];
    acc.x += ex * v.x; acc.y += ex * v.y;
    acc.z += ex * v.z; acc.w += ex * v.w;
    sum += ex;
  }
  if (e > s) {
    float inv = 1.0f / sum;
    acc.x *= inv; acc.y *= inv; acc.z *= inv; acc.w *= inv;
  }
  acc.x = fmaxf(acc.x, 0.f); acc.y = fmaxf(acc.y, 0.f);
  acc.z = fmaxf(acc.z, 0.f); acc.w = fmaxf(acc.w, 0.f);
  ((float4*)out)[(size_t)i * 64 + lane] = acc;
}

extern "C" void kernel_launch(void* const* d_in, const int* in_sizes, int n_in,
                              void* d_out, int out_size, void* d_ws, size_t ws_size,
                              hipStream_t stream) {
  const float* x   = (const float*)d_in[0];
  const float* W_w = (const float*)d_in[1];
  const float* W_b = (const float*)d_in[2];
  const float* a_w = (const float*)d_in[3];
  const float* a_b = (const float*)d_in[4];
  const int*   row = (const int*)d_in[5];
  const int*   col = (const int*)d_in[6];
  float* out = (float*)d_out;

  // workspace layout (floats; ~59 MB)
  float* ws = (float*)d_ws;
  size_t off = 0;
  float* Wh = ws + off;            off += (size_t)NP * F;      // 12.81M (padded)
  unsigned short* Wt = (unsigned short*)(ws + off); off += (F * F) / 2;  // bf16
  float* wa = ws + off;            off += 2 * F;
  float* cb = ws + off;            off += 8;
  float* f_dst = ws + off;         off += NP;
  float* f_row = ws + off;         off += NP;
  int* deg = (int*)(ws + off);     off += NP;
  int* part = (int*)(ws + off);    off += NP;
  int* bsum = (int*)(ws + off);    off += 256;
  int* boffs = (int*)(ws + off);   off += 256;
  int* row_start = (int*)(ws + off); off += NP;  // N+1 fits
  int* cursor = (int*)(ws + off);  off += NP;
  int* csr_col = (int*)(ws + off); off += N_EDGES;
  (void)ws_size; (void)in_sizes; (void)n_in; (void)out_size;

  const int NBLK = (N_NODES + 255) / 256;  // 196

  hipMemsetAsync(deg, 0, NP * sizeof(int), stream);

  hipLaunchKernelGGL(prep_w, dim3(F / 4), dim3(256), 0, stream, W_w, a_w, Wt, wa);
  hipLaunchKernelGGL(prep_scalars, dim3(1), dim3(64), 0, stream, W_b, a_w, a_b, cb);
  hipLaunchKernelGGL(gemm_mfma, dim3(NP / 128, F / 128), dim3(256), 0, stream,
                     x, Wt, W_b, Wh);
  hipLaunchKernelGGL(fvec2, dim3((N_NODES + 3) / 4), dim3(256), 0, stream,
                     x, wa, cb, f_dst, f_row);
  hipLaunchKernelGGL(deg_count, dim3((N_EDGES + 255) / 256), dim3(256), 0,
                     stream, row, deg);
  hipLaunchKernelGGL(scan1, dim3(NBLK), dim3(256), 0, stream, deg, part, bsum);
  hipLaunchKernelGGL(scan2, dim3(1), dim3(256), 0, stream, bsum, boffs, NBLK);
  hipLaunchKernelGGL(scan3, dim3(NBLK), dim3(256), 0, stream, part, boffs,
                     row_start, cursor);
  hipLaunchKernelGGL(fill_csr, dim3((N_EDGES + 255) / 256), dim3(256), 0,
                     stream, row, col, cursor, csr_col);
  hipLaunchKernelGGL(gat_pull, dim3((N_NODES + 3) / 4), dim3(256), 0, stream,
                     row_start, csr_col, f_dst, f_row, Wh, out);
}

// Round 3
// 513.728 us; speedup vs baseline: 1.6951x; 1.0742x over previous
//
#include <hip/hip_runtime.h>
#include <math.h>

#define N_NODES 50000
#define N_EDGES 1600000
#define F 256
#define ALPHA 0.2f
#define NP 50048  // padded node count (multiple of 128)

typedef short bf16x8 __attribute__((ext_vector_type(8)));
typedef float f32x4 __attribute__((ext_vector_type(4)));
typedef _Float16 half4 __attribute__((ext_vector_type(4)));

__device__ __forceinline__ unsigned short f2bf(float f) {
  union { float f; unsigned u; } v; v.f = f;
  unsigned u = v.u;
  return (unsigned short)((u + 0x7fffu + ((u >> 16) & 1u)) >> 16);
}

// ---- prep_w: W (256x256 fp32) -> Wt bf16 transposed [n][k]; wa = W @ a_halves
__global__ __launch_bounds__(256) void prep_w(const float* __restrict__ W,
                                              const float* __restrict__ a_w,
                                              unsigned short* __restrict__ Wt,
                                              float* __restrict__ wa) {
  const int lane = threadIdx.x & 63, w = threadIdx.x >> 6;
  const int k = blockIdx.x * 4 + w;  // 0..255
  float4 wv = *(const float4*)(W + (size_t)k * F + lane * 4);
  float4 a1 = *(const float4*)(a_w + lane * 4);
  float4 a2 = *(const float4*)(a_w + F + lane * 4);
  Wt[(size_t)(lane * 4 + 0) * F + k] = f2bf(wv.x);
  Wt[(size_t)(lane * 4 + 1) * F + k] = f2bf(wv.y);
  Wt[(size_t)(lane * 4 + 2) * F + k] = f2bf(wv.z);
  Wt[(size_t)(lane * 4 + 3) * F + k] = f2bf(wv.w);
  float s1 = wv.x * a1.x + wv.y * a1.y + wv.z * a1.z + wv.w * a1.w;
  float s2 = wv.x * a2.x + wv.y * a2.y + wv.z * a2.z + wv.w * a2.w;
#pragma unroll
  for (int off = 32; off > 0; off >>= 1) {
    s1 += __shfl_down(s1, off, 64);
    s2 += __shfl_down(s2, off, 64);
  }
  if (lane == 0) { wa[k] = s1; wa[F + k] = s2; }
}

// ---- prep_scalars: cb[0] = W_b.a1 ; cb[1] = W_b.a2 + a_b
__global__ __launch_bounds__(64) void prep_scalars(const float* __restrict__ W_b,
                                                   const float* __restrict__ a_w,
                                                   const float* __restrict__ a_b,
                                                   float* __restrict__ cb) {
  const int l = threadIdx.x;
  float4 b = *(const float4*)(W_b + l * 4);
  float4 a1 = *(const float4*)(a_w + l * 4);
  float4 a2 = *(const float4*)(a_w + F + l * 4);
  float s1 = b.x * a1.x + b.y * a1.y + b.z * a1.z + b.w * a1.w;
  float s2 = b.x * a2.x + b.y * a2.y + b.z * a2.z + b.w * a2.w;
#pragma unroll
  for (int off = 32; off > 0; off >>= 1) {
    s1 += __shfl_down(s1, off, 64);
    s2 += __shfl_down(s2, off, 64);
  }
  if (l == 0) { cb[0] = s1; cb[1] = s2 + a_b[0]; }
}

// ---- fvec2: exact fp32 attention projections straight from x
__global__ __launch_bounds__(256) void fvec2(const float* __restrict__ x,
                                             const float* __restrict__ wa,
                                             const float* __restrict__ cb,
                                             float* __restrict__ f_dst,
                                             float* __restrict__ f_row) {
  const int lane = threadIdx.x & 63, w = threadIdx.x >> 6;
  const int node = blockIdx.x * 4 + w;
  if (node >= N_NODES) return;
  float4 xv = *(const float4*)(x + (size_t)node * F + lane * 4);
  float4 v1 = *(const float4*)(wa + lane * 4);
  float4 v2 = *(const float4*)(wa + F + lane * 4);
  float s1 = xv.x * v1.x + xv.y * v1.y + xv.z * v1.z + xv.w * v1.w;
  float s2 = xv.x * v2.x + xv.y * v2.y + xv.z * v2.z + xv.w * v2.w;
#pragma unroll
  for (int off = 32; off > 0; off >>= 1) {
    s1 += __shfl_down(s1, off, 64);
    s2 += __shfl_down(s2, off, 64);
  }
  if (lane == 0) { f_dst[node] = s1 + cb[0]; f_row[node] = s2 + cb[1]; }
}

// ---- MFMA GEMM: Wh(fp16) = x @ W + bias, bf16 MFMA, fp32 accumulate.
#define LDSK 72
__global__ __launch_bounds__(256) void gemm_mfma(const float* __restrict__ X,
                                                 const unsigned short* __restrict__ Wt,
                                                 const float* __restrict__ bias,
                                                 _Float16* __restrict__ Wh) {
  __shared__ short As[128 * LDSK];
  __shared__ short Bs[128 * LDSK];
  const int tid = threadIdx.x;
  const int lane = tid & 63;
  const int w = tid >> 6;
  const int wm = w >> 1, wn = w & 1;
  const int m0 = blockIdx.x * 128;
  const int n0 = blockIdx.y * 128;
  f32x4 acc[4][4] = {{{0.f, 0.f, 0.f, 0.f}}};
  const int srow = tid >> 3;
  const int schunk = tid & 7;

  for (int k0 = 0; k0 < F; k0 += 64) {
#pragma unroll
    for (int i = 0; i < 4; ++i) {
      int r = i * 32 + srow;
      int gm = m0 + r; if (gm > N_NODES - 1) gm = N_NODES - 1;
      const float* src = X + (size_t)gm * F + k0 + schunk * 8;
      float4 lo = *(const float4*)src;
      float4 hi = *(const float4*)(src + 4);
      bf16x8 v;
      v[0] = (short)f2bf(lo.x); v[1] = (short)f2bf(lo.y);
      v[2] = (short)f2bf(lo.z); v[3] = (short)f2bf(lo.w);
      v[4] = (short)f2bf(hi.x); v[5] = (short)f2bf(hi.y);
      v[6] = (short)f2bf(hi.z); v[7] = (short)f2bf(hi.w);
      *(bf16x8*)&As[r * LDSK + schunk * 8] = v;
      const unsigned short* bsrc = Wt + (size_t)(n0 + r) * F + k0 + schunk * 8;
      *(bf16x8*)&Bs[r * LDSK + schunk * 8] = *(const bf16x8*)bsrc;
    }
    __syncthreads();
#pragma unroll
    for (int kk = 0; kk < 64; kk += 32) {
      const int rowsel = lane & 15;
      const int ksel = kk + (lane >> 4) * 8;
      bf16x8 af[4], bfr[4];
#pragma unroll
      for (int t = 0; t < 4; ++t) {
        af[t] = *(bf16x8*)&As[(wm * 64 + t * 16 + rowsel) * LDSK + ksel];
        bfr[t] = *(bf16x8*)&Bs[(wn * 64 + t * 16 + rowsel) * LDSK + ksel];
      }
#pragma unroll
      for (int mi = 0; mi < 4; ++mi)
#pragma unroll
        for (int nj = 0; nj < 4; ++nj)
          acc[mi][nj] = __builtin_amdgcn_mfma_f32_16x16x32_bf16(
              af[mi], bfr[nj], acc[mi][nj], 0, 0, 0);
    }
    __syncthreads();
  }
  const int crow = (lane >> 4) * 4;
  const int ccol = lane & 15;
#pragma unroll
  for (int nj = 0; nj < 4; ++nj) {
    int gc = n0 + wn * 64 + nj * 16 + ccol;
    float bv = bias[gc];
#pragma unroll
    for (int mi = 0; mi < 4; ++mi) {
      int gr = m0 + wm * 64 + mi * 16 + crow;
#pragma unroll
      for (int r = 0; r < 4; ++r)
        Wh[(size_t)(gr + r) * F + gc] = (_Float16)(acc[mi][nj][r] + bv);
    }
  }
}

// ---- degree count
__global__ __launch_bounds__(256) void deg_count(const int* __restrict__ row,
                                                 int* __restrict__ deg) {
  int k = blockIdx.x * 256 + threadIdx.x;
  if (k < N_EDGES) atomicAdd(&deg[row[k]], 1);
}

// ---- hierarchical exclusive scan (3 kernels)
__global__ __launch_bounds__(256) void scan1(const int* __restrict__ deg,
                                             int* __restrict__ part,
                                             int* __restrict__ bsum) {
  __shared__ int wsum[4];
  const int tid = threadIdx.x, lane = tid & 63, w = tid >> 6;
  const int idx = blockIdx.x * 256 + tid;
  int v = (idx < N_NODES) ? deg[idx] : 0;
  int incl = v;
#pragma unroll
  for (int off = 1; off < 64; off <<= 1) {
    int t = __shfl_up(incl, off, 64);
    if (lane >= off) incl += t;
  }
  if (lane == 63) wsum[w] = incl;
  __syncthreads();
  int prev = 0;
#pragma unroll
  for (int i = 0; i < 4; ++i) if (i < w) prev += wsum[i];
  if (idx < N_NODES) part[idx] = prev + incl - v;
  if (tid == 255) bsum[blockIdx.x] = prev + incl;
}

__global__ __launch_bounds__(256) void scan2(const int* __restrict__ bsum,
                                             int* __restrict__ boffs, int nblk) {
  __shared__ int wsum[4];
  const int tid = threadIdx.x, lane = tid & 63, w = tid >> 6;
  int v = (tid < nblk) ? bsum[tid] : 0;
  int incl = v;
#pragma unroll
  for (int off = 1; off < 64; off <<= 1) {
    int t = __shfl_up(incl, off, 64);
    if (lane >= off) incl += t;
  }
  if (lane == 63) wsum[w] = incl;
  __syncthreads();
  int prev = 0;
#pragma unroll
  for (int i = 0; i < 4; ++i) if (i < w) prev += wsum[i];
  if (tid < nblk) boffs[tid] = prev + incl - v;
}

__global__ __launch_bounds__(256) void scan3(const int* __restrict__ part,
                                             const int* __restrict__ boffs,
                                             int* __restrict__ row_start,
                                             int* __restrict__ cursor) {
  int idx = blockIdx.x * 256 + threadIdx.x;
  if (idx < N_NODES) {
    int rs = part[idx] + boffs[blockIdx.x];
    row_start[idx] = rs;
    cursor[idx] = rs;
  }
  if (idx == 0) row_start[N_NODES] = N_EDGES;
}

// ---- CSR fill (col only)
__global__ __launch_bounds__(256) void fill_csr(const int* __restrict__ row,
                                                const int* __restrict__ col,
                                                int* __restrict__ cursor,
                                                int* __restrict__ csr_col) {
  int k = blockIdx.x * 256 + threadIdx.x;
  if (k >= N_EDGES) return;
  int p = atomicAdd(&cursor[row[k]], 1);
  csr_col[p] = col[k];
}

// ---- pull: recompute attention, gather fp16 Wh rows, normalize, ReLU.
__global__ __launch_bounds__(256) void gat_pull(const int* __restrict__ row_start,
                                                const int* __restrict__ csr_col,
                                                const float* __restrict__ f_dst,
                                                const float* __restrict__ f_row,
                                                const _Float16* __restrict__ Wh,
                                                float* __restrict__ out) {
  const int lane = threadIdx.x & 63, w = threadIdx.x >> 6;
  const int i = blockIdx.x * 4 + w;
  if (i >= N_NODES) return;
  const int s = row_start[i], e = row_start[i + 1];
  const float fr = f_row[i];
  const half4* Wh4 = (const half4*)Wh;
  float4 acc = make_float4(0.f, 0.f, 0.f, 0.f);
  float sum = 0.f;
  for (int p = s; p < e; ++p) {
    int c = csr_col[p];               // wave-uniform -> broadcast load
    float ev = f_dst[c] + fr;
    ev = ev > 0.f ? ev : ALPHA * ev;
    float ex = __expf(ev);
    half4 v = Wh4[(size_t)c * 64 + lane];
    acc.x += ex * (float)v[0]; acc.y += ex * (float)v[1];
    acc.z += ex * (float)v[2]; acc.w += ex * (float)v[3];
    sum += ex;
  }
  if (e > s) {
    float inv = 1.0f / sum;
    acc.x *= inv; acc.y *= inv; acc.z *= inv; acc.w *= inv;
  }
  acc.x = fmaxf(acc.x, 0.f); acc.y = fmaxf(acc.y, 0.f);
  acc.z = fmaxf(acc.z, 0.f); acc.w = fmaxf(acc.w, 0.f);
  ((float4*)out)[(size_t)i * 64 + lane] = acc;
}

extern "C" void kernel_launch(void* const* d_in, const int* in_sizes, int n_in,
                              void* d_out, int out_size, void* d_ws, size_t ws_size,
                              hipStream_t stream) {
  const float* x   = (const float*)d_in[0];
  const float* W_w = (const float*)d_in[1];
  const float* W_b = (const float*)d_in[2];
  const float* a_w = (const float*)d_in[3];
  const float* a_b = (const float*)d_in[4];
  const int*   row = (const int*)d_in[5];
  const int*   col = (const int*)d_in[6];
  float* out = (float*)d_out;

  float* ws = (float*)d_ws;
  size_t off = 0;
  _Float16* Wh = (_Float16*)(ws + off); off += (size_t)NP * F / 2;  // fp16 table
  unsigned short* Wt = (unsigned short*)(ws + off); off += (F * F) / 2;
  float* wa = ws + off;            off += 2 * F;
  float* cb = ws + off;            off += 8;
  float* f_dst = ws + off;         off += NP;
  float* f_row = ws + off;         off += NP;
  int* deg = (int*)(ws + off);     off += NP;
  int* part = (int*)(ws + off);    off += NP;
  int* bsum = (int*)(ws + off);    off += 256;
  int* boffs = (int*)(ws + off);   off += 256;
  int* row_start = (int*)(ws + off); off += NP;
  int* cursor = (int*)(ws + off);  off += NP;
  int* csr_col = (int*)(ws + off); off += N_EDGES;
  (void)ws_size; (void)in_sizes; (void)n_in; (void)out_size;

  const int NBLK = (N_NODES + 255) / 256;  // 196

  hipMemsetAsync(deg, 0, NP * sizeof(int), stream);

  hipLaunchKernelGGL(prep_w, dim3(F / 4), dim3(256), 0, stream, W_w, a_w, Wt, wa);
  hipLaunchKernelGGL(prep_scalars, dim3(1), dim3(64), 0, stream, W_b, a_w, a_b, cb);
  hipLaunchKernelGGL(gemm_mfma, dim3(NP / 128, F / 128), dim3(256), 0, stream,
                     x, Wt, W_b, Wh);
  hipLaunchKernelGGL(fvec2, dim3((N_NODES + 3) / 4), dim3(256), 0, stream,
                     x, wa, cb, f_dst, f_row);
  hipLaunchKernelGGL(deg_count, dim3((N_EDGES + 255) / 256), dim3(256), 0,
                     stream, row, deg);
  hipLaunchKernelGGL(scan1, dim3(NBLK), dim3(256), 0, stream, deg, part, bsum);
  hipLaunchKernelGGL(scan2, dim3(1), dim3(256), 0, stream, bsum, boffs, NBLK);
  hipLaunchKernelGGL(scan3, dim3(NBLK), dim3(256), 0, stream, part, boffs,
                     row_start, cursor);
  hipLaunchKernelGGL(fill_csr, dim3((N_EDGES + 255) / 256), dim3(256), 0,
                     stream, row, col, cursor, csr_col);
  hipLaunchKernelGGL(gat_pull, dim3((N_NODES + 3) / 4), dim3(256), 0, stream,
                     row_start, csr_col, f_dst, f_row, Wh, out);
}

// Round 4
// 477.991 us; speedup vs baseline: 1.8219x; 1.0748x over previous
//
#include <hip/hip_runtime.h>
#include <math.h>

#define N_NODES 50000
#define N_EDGES 1600000
#define F 256
#define ALPHA 0.2f
#define NP 50048  // padded node count (multiple of 128)

typedef short bf16x8 __attribute__((ext_vector_type(8)));
typedef float f32x4 __attribute__((ext_vector_type(4)));
typedef _Float16 half4 __attribute__((ext_vector_type(4)));

__device__ __forceinline__ unsigned short f2bf(float f) {
  union { float f; unsigned u; } v; v.f = f;
  unsigned u = v.u;
  return (unsigned short)((u + 0x7fffu + ((u >> 16) & 1u)) >> 16);
}

// ---- prep_w: W (256x256 fp32) -> Wt bf16 transposed [n][k]; wa = W @ a_halves
__global__ __launch_bounds__(256) void prep_w(const float* __restrict__ W,
                                              const float* __restrict__ a_w,
                                              unsigned short* __restrict__ Wt,
                                              float* __restrict__ wa) {
  const int lane = threadIdx.x & 63, w = threadIdx.x >> 6;
  const int k = blockIdx.x * 4 + w;  // 0..255
  float4 wv = *(const float4*)(W + (size_t)k * F + lane * 4);
  float4 a1 = *(const float4*)(a_w + lane * 4);
  float4 a2 = *(const float4*)(a_w + F + lane * 4);
  Wt[(size_t)(lane * 4 + 0) * F + k] = f2bf(wv.x);
  Wt[(size_t)(lane * 4 + 1) * F + k] = f2bf(wv.y);
  Wt[(size_t)(lane * 4 + 2) * F + k] = f2bf(wv.z);
  Wt[(size_t)(lane * 4 + 3) * F + k] = f2bf(wv.w);
  float s1 = wv.x * a1.x + wv.y * a1.y + wv.z * a1.z + wv.w * a1.w;
  float s2 = wv.x * a2.x + wv.y * a2.y + wv.z * a2.z + wv.w * a2.w;
#pragma unroll
  for (int off = 32; off > 0; off >>= 1) {
    s1 += __shfl_down(s1, off, 64);
    s2 += __shfl_down(s2, off, 64);
  }
  if (lane == 0) { wa[k] = s1; wa[F + k] = s2; }
}

// ---- prep_scalars: cb[0] = W_b.a1 ; cb[1] = W_b.a2 + a_b
__global__ __launch_bounds__(64) void prep_scalars(const float* __restrict__ W_b,
                                                   const float* __restrict__ a_w,
                                                   const float* __restrict__ a_b,
                                                   float* __restrict__ cb) {
  const int l = threadIdx.x;
  float4 b = *(const float4*)(W_b + l * 4);
  float4 a1 = *(const float4*)(a_w + l * 4);
  float4 a2 = *(const float4*)(a_w + F + l * 4);
  float s1 = b.x * a1.x + b.y * a1.y + b.z * a1.z + b.w * a1.w;
  float s2 = b.x * a2.x + b.y * a2.y + b.z * a2.z + b.w * a2.w;
#pragma unroll
  for (int off = 32; off > 0; off >>= 1) {
    s1 += __shfl_down(s1, off, 64);
    s2 += __shfl_down(s2, off, 64);
  }
  if (l == 0) { cb[0] = s1; cb[1] = s2 + a_b[0]; }
}

// ---- fvec2: fp32 attention projections straight from x  +  x -> bf16 copy
__global__ __launch_bounds__(256) void fvec2(const float* __restrict__ x,
                                             const float* __restrict__ wa,
                                             const float* __restrict__ cb,
                                             float* __restrict__ f_dst,
                                             float* __restrict__ f_row,
                                             unsigned short* __restrict__ x_bf) {
  const int lane = threadIdx.x & 63, w = threadIdx.x >> 6;
  const int node = blockIdx.x * 4 + w;
  if (node >= N_NODES) return;
  float4 xv = *(const float4*)(x + (size_t)node * F + lane * 4);
  ushort4 xb;
  xb.x = f2bf(xv.x); xb.y = f2bf(xv.y); xb.z = f2bf(xv.z); xb.w = f2bf(xv.w);
  *(ushort4*)(x_bf + (size_t)node * F + lane * 4) = xb;
  float4 v1 = *(const float4*)(wa + lane * 4);
  float4 v2 = *(const float4*)(wa + F + lane * 4);
  float s1 = xv.x * v1.x + xv.y * v1.y + xv.z * v1.z + xv.w * v1.w;
  float s2 = xv.x * v2.x + xv.y * v2.y + xv.z * v2.z + xv.w * v2.w;
#pragma unroll
  for (int off = 32; off > 0; off >>= 1) {
    s1 += __shfl_down(s1, off, 64);
    s2 += __shfl_down(s2, off, 64);
  }
  if (lane == 0) { f_dst[node] = s1 + cb[0]; f_row[node] = s2 + cb[1]; }
}

// ---- MFMA GEMM: Wh(fp16) = x_bf @ Wt^T + bias, bf16 MFMA, fp32 accumulate.
#define LDSK 72
__global__ __launch_bounds__(256) void gemm_mfma(const unsigned short* __restrict__ Xb,
                                                 const unsigned short* __restrict__ Wt,
                                                 const float* __restrict__ bias,
                                                 _Float16* __restrict__ Wh) {
  __shared__ short As[128 * LDSK];
  __shared__ short Bs[128 * LDSK];
  const int tid = threadIdx.x;
  const int lane = tid & 63;
  const int w = tid >> 6;
  const int wm = w >> 1, wn = w & 1;
  const int m0 = blockIdx.x * 128;
  const int n0 = blockIdx.y * 128;
  f32x4 acc[4][4] = {{{0.f, 0.f, 0.f, 0.f}}};
  const int srow = tid >> 3;
  const int schunk = tid & 7;

  for (int k0 = 0; k0 < F; k0 += 64) {
#pragma unroll
    for (int i = 0; i < 4; ++i) {
      int r = i * 32 + srow;
      int gm = m0 + r; if (gm > N_NODES - 1) gm = N_NODES - 1;
      *(bf16x8*)&As[r * LDSK + schunk * 8] =
          *(const bf16x8*)(Xb + (size_t)gm * F + k0 + schunk * 8);
      *(bf16x8*)&Bs[r * LDSK + schunk * 8] =
          *(const bf16x8*)(Wt + (size_t)(n0 + r) * F + k0 + schunk * 8);
    }
    __syncthreads();
#pragma unroll
    for (int kk = 0; kk < 64; kk += 32) {
      const int rowsel = lane & 15;
      const int ksel = kk + (lane >> 4) * 8;
      bf16x8 af[4], bfr[4];
#pragma unroll
      for (int t = 0; t < 4; ++t) {
        af[t] = *(bf16x8*)&As[(wm * 64 + t * 16 + rowsel) * LDSK + ksel];
        bfr[t] = *(bf16x8*)&Bs[(wn * 64 + t * 16 + rowsel) * LDSK + ksel];
      }
#pragma unroll
      for (int mi = 0; mi < 4; ++mi)
#pragma unroll
        for (int nj = 0; nj < 4; ++nj)
          acc[mi][nj] = __builtin_amdgcn_mfma_f32_16x16x32_bf16(
              af[mi], bfr[nj], acc[mi][nj], 0, 0, 0);
    }
    __syncthreads();
  }
  const int crow = (lane >> 4) * 4;
  const int ccol = lane & 15;
#pragma unroll
  for (int nj = 0; nj < 4; ++nj) {
    int gc = n0 + wn * 64 + nj * 16 + ccol;
    float bv = bias[gc];
#pragma unroll
    for (int mi = 0; mi < 4; ++mi) {
      int gr = m0 + wm * 64 + mi * 16 + crow;
#pragma unroll
      for (int r = 0; r < 4; ++r)
        Wh[(size_t)(gr + r) * F + gc] = (_Float16)(acc[mi][nj][r] + bv);
    }
  }
}

// ---- degree count
__global__ __launch_bounds__(256) void deg_count(const int* __restrict__ row,
                                                 int* __restrict__ deg) {
  int k = blockIdx.x * 256 + threadIdx.x;
  if (k < N_EDGES) atomicAdd(&deg[row[k]], 1);
}

// ---- hierarchical exclusive scan (3 kernels)
__global__ __launch_bounds__(256) void scan1(const int* __restrict__ deg,
                                             int* __restrict__ part,
                                             int* __restrict__ bsum) {
  __shared__ int wsum[4];
  const int tid = threadIdx.x, lane = tid & 63, w = tid >> 6;
  const int idx = blockIdx.x * 256 + tid;
  int v = (idx < N_NODES) ? deg[idx] : 0;
  int incl = v;
#pragma unroll
  for (int off = 1; off < 64; off <<= 1) {
    int t = __shfl_up(incl, off, 64);
    if (lane >= off) incl += t;
  }
  if (lane == 63) wsum[w] = incl;
  __syncthreads();
  int prev = 0;
#pragma unroll
  for (int i = 0; i < 4; ++i) if (i < w) prev += wsum[i];
  if (idx < N_NODES) part[idx] = prev + incl - v;
  if (tid == 255) bsum[blockIdx.x] = prev + incl;
}

__global__ __launch_bounds__(256) void scan2(const int* __restrict__ bsum,
                                             int* __restrict__ boffs, int nblk) {
  __shared__ int wsum[4];
  const int tid = threadIdx.x, lane = tid & 63, w = tid >> 6;
  int v = (tid < nblk) ? bsum[tid] : 0;
  int incl = v;
#pragma unroll
  for (int off = 1; off < 64; off <<= 1) {
    int t = __shfl_up(incl, off, 64);
    if (lane >= off) incl += t;
  }
  if (lane == 63) wsum[w] = incl;
  __syncthreads();
  int prev = 0;
#pragma unroll
  for (int i = 0; i < 4; ++i) if (i < w) prev += wsum[i];
  if (tid < nblk) boffs[tid] = prev + incl - v;
}

__global__ __launch_bounds__(256) void scan3(const int* __restrict__ part,
                                             const int* __restrict__ boffs,
                                             int* __restrict__ row_start,
                                             int* __restrict__ cursor) {
  int idx = blockIdx.x * 256 + threadIdx.x;
  if (idx < N_NODES) {
    int rs = part[idx] + boffs[blockIdx.x];
    row_start[idx] = rs;
    cursor[idx] = rs;
  }
  if (idx == 0) row_start[N_NODES] = N_EDGES;
}

// ---- CSR fill (col only)
__global__ __launch_bounds__(256) void fill_csr(const int* __restrict__ row,
                                                const int* __restrict__ col,
                                                int* __restrict__ cursor,
                                                int* __restrict__ csr_col) {
  int k = blockIdx.x * 256 + threadIdx.x;
  if (k >= N_EDGES) return;
  int p = atomicAdd(&cursor[row[k]], 1);
  csr_col[p] = col[k];
}

// ---- pull: 8-deep unrolled gather pipeline. One wave per row.
__global__ __launch_bounds__(256) void gat_pull(const int* __restrict__ row_start,
                                                const int* __restrict__ csr_col,
                                                const float* __restrict__ f_dst,
                                                const float* __restrict__ f_row,
                                                const _Float16* __restrict__ Wh,
                                                float* __restrict__ out) {
  const int lane = threadIdx.x & 63, w = threadIdx.x >> 6;
  const int i = blockIdx.x * 4 + w;
  if (i >= N_NODES) return;
  const int s = row_start[i], e = row_start[i + 1];
  const float fr = f_row[i];
  const half4* Wh4 = (const half4*)Wh;
  float4 acc = make_float4(0.f, 0.f, 0.f, 0.f);
  float sum = 0.f;
  if (e > s) {
    for (int p = s; p < e; p += 8) {
      int c[8];
      float xw[8];
#pragma unroll
      for (int j = 0; j < 8; ++j) {
        int q = p + j;
        c[j] = csr_col[q < e ? q : s];  // clamp: redundant gathers hit L1
      }
      half4 v[8];
#pragma unroll
      for (int j = 0; j < 8; ++j) v[j] = Wh4[(size_t)c[j] * 64 + lane];
#pragma unroll
      for (int j = 0; j < 8; ++j) {
        float ev = f_dst[c[j]] + fr;
        ev = ev > 0.f ? ev : ALPHA * ev;
        xw[j] = (p + j < e) ? __expf(ev) : 0.f;
        sum += xw[j];
      }
#pragma unroll
      for (int j = 0; j < 8; ++j) {
        acc.x += xw[j] * (float)v[j][0];
        acc.y += xw[j] * (float)v[j][1];
        acc.z += xw[j] * (float)v[j][2];
        acc.w += xw[j] * (float)v[j][3];
      }
    }
    float inv = 1.0f / sum;
    acc.x *= inv; acc.y *= inv; acc.z *= inv; acc.w *= inv;
  }
  acc.x = fmaxf(acc.x, 0.f); acc.y = fmaxf(acc.y, 0.f);
  acc.z = fmaxf(acc.z, 0.f); acc.w = fmaxf(acc.w, 0.f);
  ((float4*)out)[(size_t)i * 64 + lane] = acc;
}

extern "C" void kernel_launch(void* const* d_in, const int* in_sizes, int n_in,
                              void* d_out, int out_size, void* d_ws, size_t ws_size,
                              hipStream_t stream) {
  const float* x   = (const float*)d_in[0];
  const float* W_w = (const float*)d_in[1];
  const float* W_b = (const float*)d_in[2];
  const float* a_w = (const float*)d_in[3];
  const float* a_b = (const float*)d_in[4];
  const int*   row = (const int*)d_in[5];
  const int*   col = (const int*)d_in[6];
  float* out = (float*)d_out;

  float* ws = (float*)d_ws;
  size_t off = 0;
  _Float16* Wh = (_Float16*)(ws + off); off += (size_t)NP * F / 2;       // fp16
  unsigned short* x_bf = (unsigned short*)(ws + off); off += (size_t)NP * F / 2;
  unsigned short* Wt = (unsigned short*)(ws + off); off += (F * F) / 2;  // bf16
  float* wa = ws + off;            off += 2 * F;
  float* cb = ws + off;            off += 8;
  float* f_dst = ws + off;         off += NP;
  float* f_row = ws + off;         off += NP;
  int* deg = (int*)(ws + off);     off += NP;
  int* part = (int*)(ws + off);    off += NP;
  int* bsum = (int*)(ws + off);    off += 256;
  int* boffs = (int*)(ws + off);   off += 256;
  int* row_start = (int*)(ws + off); off += NP;
  int* cursor = (int*)(ws + off);  off += NP;
  int* csr_col = (int*)(ws + off); off += N_EDGES;
  (void)ws_size; (void)in_sizes; (void)n_in; (void)out_size;

  const int NBLK = (N_NODES + 255) / 256;  // 196

  hipMemsetAsync(deg, 0, NP * sizeof(int), stream);

  hipLaunchKernelGGL(prep_w, dim3(F / 4), dim3(256), 0, stream, W_w, a_w, Wt, wa);
  hipLaunchKernelGGL(prep_scalars, dim3(1), dim3(64), 0, stream, W_b, a_w, a_b, cb);
  hipLaunchKernelGGL(fvec2, dim3((N_NODES + 3) / 4), dim3(256), 0, stream,
                     x, wa, cb, f_dst, f_row, x_bf);
  hipLaunchKernelGGL(gemm_mfma, dim3(NP / 128, F / 128), dim3(256), 0, stream,
                     x_bf, Wt, W_b, Wh);
  hipLaunchKernelGGL(deg_count, dim3((N_EDGES + 255) / 256), dim3(256), 0,
                     stream, row, deg);
  hipLaunchKernelGGL(scan1, dim3(NBLK), dim3(256), 0, stream, deg, part, bsum);
  hipLaunchKernelGGL(scan2, dim3(1), dim3(256), 0, stream, bsum, boffs, NBLK);
  hipLaunchKernelGGL(scan3, dim3(NBLK), dim3(256), 0, stream, part, boffs,
                     row_start, cursor);
  hipLaunchKernelGGL(fill_csr, dim3((N_EDGES + 255) / 256), dim3(256), 0,
                     stream, row, col, cursor, csr_col);
  hipLaunchKernelGGL(gat_pull, dim3((N_NODES + 3) / 4), dim3(256), 0, stream,
                     row_start, csr_col, f_dst, f_row, Wh, out);
}

// Round 5
// 344.670 us; speedup vs baseline: 2.5266x; 1.3868x over previous
//
#include <hip/hip_runtime.h>
#include <math.h>

#define N_NODES 50000
#define N_EDGES 1600000
#define F 256
#define ALPHA 0.2f
#define NP 50048   // padded node count (multiple of 128)
#define NB 196     // coarse buckets: bucket = row >> 8 (256 rows each)
#define EPB 4096   // edges per binning block
#define NAB ((N_EDGES + EPB - 1) / EPB)  // 391

typedef short bf16x8 __attribute__((ext_vector_type(8)));
typedef float f32x4 __attribute__((ext_vector_type(4)));
typedef _Float16 half4 __attribute__((ext_vector_type(4)));

__device__ __forceinline__ unsigned short f2bf(float f) {
  union { float f; unsigned u; } v; v.f = f;
  unsigned u = v.u;
  return (unsigned short)((u + 0x7fffu + ((u >> 16) & 1u)) >> 16);
}

// ---- prep_w: W (256x256 fp32) -> Wt bf16 transposed [n][k]; wa = W @ a_halves
__global__ __launch_bounds__(256) void prep_w(const float* __restrict__ W,
                                              const float* __restrict__ a_w,
                                              unsigned short* __restrict__ Wt,
                                              float* __restrict__ wa) {
  const int lane = threadIdx.x & 63, w = threadIdx.x >> 6;
  const int k = blockIdx.x * 4 + w;  // 0..255
  float4 wv = *(const float4*)(W + (size_t)k * F + lane * 4);
  float4 a1 = *(const float4*)(a_w + lane * 4);
  float4 a2 = *(const float4*)(a_w + F + lane * 4);
  Wt[(size_t)(lane * 4 + 0) * F + k] = f2bf(wv.x);
  Wt[(size_t)(lane * 4 + 1) * F + k] = f2bf(wv.y);
  Wt[(size_t)(lane * 4 + 2) * F + k] = f2bf(wv.z);
  Wt[(size_t)(lane * 4 + 3) * F + k] = f2bf(wv.w);
  float s1 = wv.x * a1.x + wv.y * a1.y + wv.z * a1.z + wv.w * a1.w;
  float s2 = wv.x * a2.x + wv.y * a2.y + wv.z * a2.z + wv.w * a2.w;
#pragma unroll
  for (int off = 32; off > 0; off >>= 1) {
    s1 += __shfl_down(s1, off, 64);
    s2 += __shfl_down(s2, off, 64);
  }
  if (lane == 0) { wa[k] = s1; wa[F + k] = s2; }
}

// ---- prep_scalars: cb[0] = W_b.a1 ; cb[1] = W_b.a2 + a_b
__global__ __launch_bounds__(64) void prep_scalars(const float* __restrict__ W_b,
                                                   const float* __restrict__ a_w,
                                                   const float* __restrict__ a_b,
                                                   float* __restrict__ cb) {
  const int l = threadIdx.x;
  float4 b = *(const float4*)(W_b + l * 4);
  float4 a1 = *(const float4*)(a_w + l * 4);
  float4 a2 = *(const float4*)(a_w + F + l * 4);
  float s1 = b.x * a1.x + b.y * a1.y + b.z * a1.z + b.w * a1.w;
  float s2 = b.x * a2.x + b.y * a2.y + b.z * a2.z + b.w * a2.w;
#pragma unroll
  for (int off = 32; off > 0; off >>= 1) {
    s1 += __shfl_down(s1, off, 64);
    s2 += __shfl_down(s2, off, 64);
  }
  if (l == 0) { cb[0] = s1; cb[1] = s2 + a_b[0]; }
}

// ---- fvec2: fp32 attention projections straight from x  +  x -> bf16 copy
__global__ __launch_bounds__(256) void fvec2(const float* __restrict__ x,
                                             const float* __restrict__ wa,
                                             const float* __restrict__ cb,
                                             float* __restrict__ f_dst,
                                             float* __restrict__ f_row,
                                             unsigned short* __restrict__ x_bf) {
  const int lane = threadIdx.x & 63, w = threadIdx.x >> 6;
  const int node = blockIdx.x * 4 + w;
  if (node >= N_NODES) return;
  float4 xv = *(const float4*)(x + (size_t)node * F + lane * 4);
  ushort4 xb;
  xb.x = f2bf(xv.x); xb.y = f2bf(xv.y); xb.z = f2bf(xv.z); xb.w = f2bf(xv.w);
  *(ushort4*)(x_bf + (size_t)node * F + lane * 4) = xb;
  float4 v1 = *(const float4*)(wa + lane * 4);
  float4 v2 = *(const float4*)(wa + F + lane * 4);
  float s1 = xv.x * v1.x + xv.y * v1.y + xv.z * v1.z + xv.w * v1.w;
  float s2 = xv.x * v2.x + xv.y * v2.y + xv.z * v2.z + xv.w * v2.w;
#pragma unroll
  for (int off = 32; off > 0; off >>= 1) {
    s1 += __shfl_down(s1, off, 64);
    s2 += __shfl_down(s2, off, 64);
  }
  if (lane == 0) { f_dst[node] = s1 + cb[0]; f_row[node] = s2 + cb[1]; }
}

// ---- MFMA GEMM: Wh(fp16) = x_bf @ Wt^T + bias, bf16 MFMA, fp32 accumulate.
#define LDSK 72
__global__ __launch_bounds__(256) void gemm_mfma(const unsigned short* __restrict__ Xb,
                                                 const unsigned short* __restrict__ Wt,
                                                 const float* __restrict__ bias,
                                                 _Float16* __restrict__ Wh) {
  __shared__ short As[128 * LDSK];
  __shared__ short Bs[128 * LDSK];
  const int tid = threadIdx.x;
  const int lane = tid & 63;
  const int w = tid >> 6;
  const int wm = w >> 1, wn = w & 1;
  const int m0 = blockIdx.x * 128;
  const int n0 = blockIdx.y * 128;
  f32x4 acc[4][4] = {{{0.f, 0.f, 0.f, 0.f}}};
  const int srow = tid >> 3;
  const int schunk = tid & 7;

  for (int k0 = 0; k0 < F; k0 += 64) {
#pragma unroll
    for (int i = 0; i < 4; ++i) {
      int r = i * 32 + srow;
      int gm = m0 + r; if (gm > N_NODES - 1) gm = N_NODES - 1;
      *(bf16x8*)&As[r * LDSK + schunk * 8] =
          *(const bf16x8*)(Xb + (size_t)gm * F + k0 + schunk * 8);
      *(bf16x8*)&Bs[r * LDSK + schunk * 8] =
          *(const bf16x8*)(Wt + (size_t)(n0 + r) * F + k0 + schunk * 8);
    }
    __syncthreads();
#pragma unroll
    for (int kk = 0; kk < 64; kk += 32) {
      const int rowsel = lane & 15;
      const int ksel = kk + (lane >> 4) * 8;
      bf16x8 af[4], bfr[4];
#pragma unroll
      for (int t = 0; t < 4; ++t) {
        af[t] = *(bf16x8*)&As[(wm * 64 + t * 16 + rowsel) * LDSK + ksel];
        bfr[t] = *(bf16x8*)&Bs[(wn * 64 + t * 16 + rowsel) * LDSK + ksel];
      }
#pragma unroll
      for (int mi = 0; mi < 4; ++mi)
#pragma unroll
        for (int nj = 0; nj < 4; ++nj)
          acc[mi][nj] = __builtin_amdgcn_mfma_f32_16x16x32_bf16(
              af[mi], bfr[nj], acc[mi][nj], 0, 0, 0);
    }
    __syncthreads();
  }
  const int crow = (lane >> 4) * 4;
  const int ccol = lane & 15;
#pragma unroll
  for (int nj = 0; nj < 4; ++nj) {
    int gc = n0 + wn * 64 + nj * 16 + ccol;
    float bv = bias[gc];
#pragma unroll
    for (int mi = 0; mi < 4; ++mi) {
      int gr = m0 + wm * 64 + mi * 16 + crow;
#pragma unroll
      for (int r = 0; r < 4; ++r)
        Wh[(size_t)(gr + r) * F + gc] = (_Float16)(acc[mi][nj][r] + bv);
    }
  }
}

// ---- binA1: coarse bucket histogram (LDS-aggregated)
__global__ __launch_bounds__(256) void binA1(const int* __restrict__ row,
                                             int* __restrict__ ghist) {
  __shared__ int h[NB];
  const int t = threadIdx.x;
  for (int i = t; i < NB; i += 256) h[i] = 0;
  __syncthreads();
  const int base = blockIdx.x * EPB;
#pragma unroll
  for (int j = 0; j < 16; ++j) {
    int k = base + j * 256 + t;
    if (k < N_EDGES) atomicAdd(&h[row[k] >> 8], 1);
  }
  __syncthreads();
  for (int i = t; i < NB; i += 256)
    if (h[i]) atomicAdd(&ghist[i], h[i]);
}

// ---- binScan: scan bucket sizes -> bases + cursors; row_start[N] = E
__global__ __launch_bounds__(256) void binScan(const int* __restrict__ ghist,
                                               int* __restrict__ bbase,
                                               int* __restrict__ gcur,
                                               int* __restrict__ row_start) {
  __shared__ int h[NB];
  const int t = threadIdx.x;
  if (t < NB) h[t] = ghist[t];
  __syncthreads();
  if (t == 0) {
    int run = 0;
    for (int i = 0; i < NB; ++i) { int v = h[i]; h[i] = run; run += v; }
  }
  __syncthreads();
  if (t < NB) { bbase[t] = h[t]; gcur[t] = h[t]; }
  if (t == 0) row_start[N_NODES] = N_EDGES;
}

// ---- binA2: group 4096 edges by bucket in LDS, copy out bucket-contiguous
__global__ __launch_bounds__(256) void binA2(const int* __restrict__ row,
                                             const int* __restrict__ col,
                                             int* __restrict__ gcur,
                                             unsigned* __restrict__ gstage) {
  __shared__ int h[NB], lofs[NB], lcur[NB], gb[NB];
  __shared__ unsigned stage[EPB];
  const int t = threadIdx.x;
  for (int i = t; i < NB; i += 256) { h[i] = 0; lcur[i] = 0; }
  __syncthreads();
  const int base = blockIdx.x * EPB;
  const int cnt = min(EPB, N_EDGES - base);
#pragma unroll
  for (int j = 0; j < 16; ++j) {
    int k = base + j * 256 + t;
    if (k < N_EDGES) atomicAdd(&h[row[k] >> 8], 1);
  }
  __syncthreads();
  if (t == 0) {
    int run = 0;
    for (int i = 0; i < NB; ++i) { lofs[i] = run; run += h[i]; }
  }
  __syncthreads();
  if (t < NB && h[t] > 0) gb[t] = atomicAdd(&gcur[t], h[t]);
  __syncthreads();
#pragma unroll
  for (int j = 0; j < 16; ++j) {
    int k = base + j * 256 + t;
    if (k < N_EDGES) {
      int r = row[k], b = r >> 8;
      int lp = lofs[b] + atomicAdd(&lcur[b], 1);
      stage[lp] = ((unsigned)b << 24) | ((unsigned)(r & 255) << 16) |
                  (unsigned)col[k];
    }
  }
  __syncthreads();
#pragma unroll
  for (int j = 0; j < 16; ++j) {
    int s = j * 256 + t;
    if (s < cnt) {
      unsigned wv = stage[s];
      int b = wv >> 24;
      gstage[gb[b] + (s - lofs[b])] = wv & 0x00FFFFFFu;  // (localrow,col)
    }
  }
}

// ---- binB: one block per bucket: per-row counts -> row_start, place csr_col
__global__ __launch_bounds__(256) void binB(const int* __restrict__ ghist,
                                            const int* __restrict__ bbase,
                                            const unsigned* __restrict__ gstage,
                                            int* __restrict__ row_start,
                                            unsigned short* __restrict__ csr_col) {
  __shared__ int cnt[256], cur[256];
  const int t = threadIdx.x;
  const int b = blockIdx.x;
  cnt[t] = 0;
  __syncthreads();
  const int nb = ghist[b], start = bbase[b];
  for (int s = t; s < nb; s += 256) {
    unsigned wv = gstage[start + s];
    atomicAdd(&cnt[(wv >> 16) & 255], 1);
  }
  __syncthreads();
  if (t == 0) {
    int run = 0;
    for (int i = 0; i < 256; ++i) { int v = cnt[i]; cur[i] = run; run += v; }
  }
  __syncthreads();
  const int gr = (b << 8) + t;
  const int myoff = cur[t];
  if (gr < N_NODES) row_start[gr] = start + myoff;
  __syncthreads();
  for (int s = t; s < nb; s += 256) {
    unsigned wv = gstage[start + s];
    int lr = (wv >> 16) & 255;
    int p = start + atomicAdd(&cur[lr], 1);
    csr_col[p] = (unsigned short)(wv & 0xFFFFu);
  }
}

// ---- pull: 8-deep unrolled gather pipeline. One wave per row.
__global__ __launch_bounds__(256) void gat_pull(const int* __restrict__ row_start,
                                                const unsigned short* __restrict__ csr_col,
                                                const float* __restrict__ f_dst,
                                                const float* __restrict__ f_row,
                                                const _Float16* __restrict__ Wh,
                                                float* __restrict__ out) {
  const int lane = threadIdx.x & 63, w = threadIdx.x >> 6;
  const int i = blockIdx.x * 4 + w;
  if (i >= N_NODES) return;
  const int s = row_start[i], e = row_start[i + 1];
  const float fr = f_row[i];
  const half4* Wh4 = (const half4*)Wh;
  float4 acc = make_float4(0.f, 0.f, 0.f, 0.f);
  float sum = 0.f;
  if (e > s) {
    for (int p = s; p < e; p += 8) {
      int c[8];
      float xw[8];
#pragma unroll
      for (int j = 0; j < 8; ++j) {
        int q = p + j;
        c[j] = csr_col[q < e ? q : s];  // clamp: redundant gathers hit L1
      }
      half4 v[8];
#pragma unroll
      for (int j = 0; j < 8; ++j) v[j] = Wh4[(size_t)c[j] * 64 + lane];
#pragma unroll
      for (int j = 0; j < 8; ++j) {
        float ev = f_dst[c[j]] + fr;
        ev = ev > 0.f ? ev : ALPHA * ev;
        xw[j] = (p + j < e) ? __expf(ev) : 0.f;
        sum += xw[j];
      }
#pragma unroll
      for (int j = 0; j < 8; ++j) {
        acc.x += xw[j] * (float)v[j][0];
        acc.y += xw[j] * (float)v[j][1];
        acc.z += xw[j] * (float)v[j][2];
        acc.w += xw[j] * (float)v[j][3];
      }
    }
    float inv = 1.0f / sum;
    acc.x *= inv; acc.y *= inv; acc.z *= inv; acc.w *= inv;
  }
  acc.x = fmaxf(acc.x, 0.f); acc.y = fmaxf(acc.y, 0.f);
  acc.z = fmaxf(acc.z, 0.f); acc.w = fmaxf(acc.w, 0.f);
  ((float4*)out)[(size_t)i * 64 + lane] = acc;
}

extern "C" void kernel_launch(void* const* d_in, const int* in_sizes, int n_in,
                              void* d_out, int out_size, void* d_ws, size_t ws_size,
                              hipStream_t stream) {
  const float* x   = (const float*)d_in[0];
  const float* W_w = (const float*)d_in[1];
  const float* W_b = (const float*)d_in[2];
  const float* a_w = (const float*)d_in[3];
  const float* a_b = (const float*)d_in[4];
  const int*   row = (const int*)d_in[5];
  const int*   col = (const int*)d_in[6];
  float* out = (float*)d_out;

  float* ws = (float*)d_ws;
  size_t off = 0;
  _Float16* Wh = (_Float16*)(ws + off); off += (size_t)NP * F / 2;       // fp16
  unsigned short* x_bf = (unsigned short*)(ws + off); off += (size_t)NP * F / 2;
  unsigned short* Wt = (unsigned short*)(ws + off); off += (F * F) / 2;  // bf16
  float* wa = ws + off;            off += 2 * F;
  float* cb = ws + off;            off += 8;
  float* f_dst = ws + off;         off += NP;
  float* f_row = ws + off;         off += NP;
  int* ghist = (int*)(ws + off);   off += NB;     // memset 0
  int* bbase = (int*)(ws + off);   off += NB;
  int* gcur = (int*)(ws + off);    off += NB;
  int* row_start = (int*)(ws + off); off += NP;   // N+1 fits
  unsigned* gstage = (unsigned*)(ws + off); off += N_EDGES;
  unsigned short* csr_col = (unsigned short*)(ws + off); off += N_EDGES / 2;
  (void)ws_size; (void)in_sizes; (void)n_in; (void)out_size;

  hipMemsetAsync(ghist, 0, NB * sizeof(int), stream);

  hipLaunchKernelGGL(prep_w, dim3(F / 4), dim3(256), 0, stream, W_w, a_w, Wt, wa);
  hipLaunchKernelGGL(prep_scalars, dim3(1), dim3(64), 0, stream, W_b, a_w, a_b, cb);
  hipLaunchKernelGGL(fvec2, dim3((N_NODES + 3) / 4), dim3(256), 0, stream,
                     x, wa, cb, f_dst, f_row, x_bf);
  hipLaunchKernelGGL(gemm_mfma, dim3(NP / 128, F / 128), dim3(256), 0, stream,
                     x_bf, Wt, W_b, Wh);
  hipLaunchKernelGGL(binA1, dim3(NAB), dim3(256), 0, stream, row, ghist);
  hipLaunchKernelGGL(binScan, dim3(1), dim3(256), 0, stream, ghist, bbase,
                     gcur, row_start);
  hipLaunchKernelGGL(binA2, dim3(NAB), dim3(256), 0, stream, row, col, gcur,
                     gstage);
  hipLaunchKernelGGL(binB, dim3(NB), dim3(256), 0, stream, ghist, bbase,
                     gstage, row_start, csr_col);
  hipLaunchKernelGGL(gat_pull, dim3((N_NODES + 3) / 4), dim3(256), 0, stream,
                     row_start, csr_col, f_dst, f_row, Wh, out);
}

// Round 7
// 328.395 us; speedup vs baseline: 2.6518x; 1.0496x over previous
//
#include <hip/hip_runtime.h>
#include <math.h>

#define N_NODES 50000
#define N_EDGES 1600000
#define F 256
#define ALPHA 0.2f
#define NP 50048   // padded node count (multiple of 128)
#define NB 196     // coarse buckets: bucket = row >> 8 (256 rows each)
#define EPB 4096   // edges per binning block
#define NAB ((N_EDGES + EPB - 1) / EPB)  // 391

typedef short bf16x8 __attribute__((ext_vector_type(8)));
typedef float f32x4 __attribute__((ext_vector_type(4)));
typedef _Float16 half4 __attribute__((ext_vector_type(4)));

__device__ __forceinline__ unsigned short f2bf(float f) {
  union { float f; unsigned u; } v; v.f = f;
  unsigned u = v.u;
  return (unsigned short)((u + 0x7fffu + ((u >> 16) & 1u)) >> 16);
}

__device__ __forceinline__ unsigned short f2h_bits(float f) {
  union { _Float16 h; unsigned short u; } v;
  v.h = (_Float16)f;
  return v.u;
}

__device__ __forceinline__ float h_bits2f(unsigned short u) {
  union { _Float16 h; unsigned short u; } v;
  v.u = u;
  return (float)v.h;
}

// ---- prep_w: W -> Wt bf16 transposed [n][k]; wa = W @ a_halves; cb scalars
__global__ __launch_bounds__(256) void prep_w(const float* __restrict__ W,
                                              const float* __restrict__ a_w,
                                              const float* __restrict__ W_b,
                                              const float* __restrict__ a_b,
                                              unsigned short* __restrict__ Wt,
                                              float* __restrict__ wa,
                                              float* __restrict__ cb) {
  const int lane = threadIdx.x & 63, w = threadIdx.x >> 6;
  const int k = blockIdx.x * 4 + w;  // 0..255
  float4 wv = *(const float4*)(W + (size_t)k * F + lane * 4);
  float4 a1 = *(const float4*)(a_w + lane * 4);
  float4 a2 = *(const float4*)(a_w + F + lane * 4);
  Wt[(size_t)(lane * 4 + 0) * F + k] = f2bf(wv.x);
  Wt[(size_t)(lane * 4 + 1) * F + k] = f2bf(wv.y);
  Wt[(size_t)(lane * 4 + 2) * F + k] = f2bf(wv.z);
  Wt[(size_t)(lane * 4 + 3) * F + k] = f2bf(wv.w);
  float s1 = wv.x * a1.x + wv.y * a1.y + wv.z * a1.z + wv.w * a1.w;
  float s2 = wv.x * a2.x + wv.y * a2.y + wv.z * a2.z + wv.w * a2.w;
#pragma unroll
  for (int off = 32; off > 0; off >>= 1) {
    s1 += __shfl_down(s1, off, 64);
    s2 += __shfl_down(s2, off, 64);
  }
  if (lane == 0) { wa[k] = s1; wa[F + k] = s2; }
  // fold constants: cb[0] = W_b.a1 ; cb[1] = W_b.a2 + a_b  (block 0, wave 0)
  if (blockIdx.x == 0 && w == 0) {
    float4 b = *(const float4*)(W_b + lane * 4);
    float t1 = b.x * a1.x + b.y * a1.y + b.z * a1.z + b.w * a1.w;
    float t2 = b.x * a2.x + b.y * a2.y + b.z * a2.z + b.w * a2.w;
#pragma unroll
    for (int off = 32; off > 0; off >>= 1) {
      t1 += __shfl_down(t1, off, 64);
      t2 += __shfl_down(t2, off, 64);
    }
    if (lane == 0) { cb[0] = t1; cb[1] = t2 + a_b[0]; }
  }
}

// ---- fvec2: fp32 attention projections straight from x  +  x -> bf16 copy
__global__ __launch_bounds__(256) void fvec2(const float* __restrict__ x,
                                             const float* __restrict__ wa,
                                             const float* __restrict__ cb,
                                             float* __restrict__ f_dst,
                                             float* __restrict__ f_row,
                                             unsigned short* __restrict__ x_bf) {
  const int lane = threadIdx.x & 63, w = threadIdx.x >> 6;
  const int node = blockIdx.x * 4 + w;
  if (node >= N_NODES) return;
  float4 xv = *(const float4*)(x + (size_t)node * F + lane * 4);
  ushort4 xb;
  xb.x = f2bf(xv.x); xb.y = f2bf(xv.y); xb.z = f2bf(xv.z); xb.w = f2bf(xv.w);
  *(ushort4*)(x_bf + (size_t)node * F + lane * 4) = xb;
  float4 v1 = *(const float4*)(wa + lane * 4);
  float4 v2 = *(const float4*)(wa + F + lane * 4);
  float s1 = xv.x * v1.x + xv.y * v1.y + xv.z * v1.z + xv.w * v1.w;
  float s2 = xv.x * v2.x + xv.y * v2.y + xv.z * v2.z + xv.w * v2.w;
#pragma unroll
  for (int off = 32; off > 0; off >>= 1) {
    s1 += __shfl_down(s1, off, 64);
    s2 += __shfl_down(s2, off, 64);
  }
  if (lane == 0) { f_dst[node] = s1 + cb[0]; f_row[node] = s2 + cb[1]; }
}

// ---- MFMA GEMM: Wh(fp16) = x_bf @ Wt^T + bias (round-5 proven staging)
#define LDSK 72
__global__ __launch_bounds__(256) void gemm_mfma(const unsigned short* __restrict__ Xb,
                                                 const unsigned short* __restrict__ Wt,
                                                 const float* __restrict__ bias,
                                                 _Float16* __restrict__ Wh) {
  __shared__ short As[128 * LDSK];
  __shared__ short Bs[128 * LDSK];
  const int tid = threadIdx.x;
  const int lane = tid & 63;
  const int w = tid >> 6;
  const int wm = w >> 1, wn = w & 1;
  const int m0 = blockIdx.x * 128;
  const int n0 = blockIdx.y * 128;
  f32x4 acc[4][4] = {{{0.f, 0.f, 0.f, 0.f}}};
  const int srow = tid >> 3;
  const int schunk = tid & 7;

  for (int k0 = 0; k0 < F; k0 += 64) {
#pragma unroll
    for (int i = 0; i < 4; ++i) {
      int r = i * 32 + srow;
      int gm = m0 + r; if (gm > N_NODES - 1) gm = N_NODES - 1;
      *(bf16x8*)&As[r * LDSK + schunk * 8] =
          *(const bf16x8*)(Xb + (size_t)gm * F + k0 + schunk * 8);
      *(bf16x8*)&Bs[r * LDSK + schunk * 8] =
          *(const bf16x8*)(Wt + (size_t)(n0 + r) * F + k0 + schunk * 8);
    }
    __syncthreads();
#pragma unroll
    for (int kk = 0; kk < 64; kk += 32) {
      const int rowsel = lane & 15;
      const int ksel = kk + (lane >> 4) * 8;
      bf16x8 af[4], bfr[4];
#pragma unroll
      for (int t = 0; t < 4; ++t) {
        af[t] = *(bf16x8*)&As[(wm * 64 + t * 16 + rowsel) * LDSK + ksel];
        bfr[t] = *(bf16x8*)&Bs[(wn * 64 + t * 16 + rowsel) * LDSK + ksel];
      }
#pragma unroll
      for (int mi = 0; mi < 4; ++mi)
#pragma unroll
        for (int nj = 0; nj < 4; ++nj)
          acc[mi][nj] = __builtin_amdgcn_mfma_f32_16x16x32_bf16(
              af[mi], bfr[nj], acc[mi][nj], 0, 0, 0);
    }
    __syncthreads();
  }
  const int crow = (lane >> 4) * 4;
  const int ccol = lane & 15;
#pragma unroll
  for (int nj = 0; nj < 4; ++nj) {
    int gc = n0 + wn * 64 + nj * 16 + ccol;
    float bv = bias[gc];
#pragma unroll
    for (int mi = 0; mi < 4; ++mi) {
      int gr = m0 + wm * 64 + mi * 16 + crow;
#pragma unroll
      for (int r = 0; r < 4; ++r)
        Wh[(size_t)(gr + r) * F + gc] = (_Float16)(acc[mi][nj][r] + bv);
    }
  }
}

// ---- binA1: coarse bucket histogram (LDS-aggregated)
__global__ __launch_bounds__(256) void binA1(const int* __restrict__ row,
                                             int* __restrict__ ghist) {
  __shared__ int h[NB];
  const int t = threadIdx.x;
  for (int i = t; i < NB; i += 256) h[i] = 0;
  __syncthreads();
  const int base = blockIdx.x * EPB;
#pragma unroll
  for (int j = 0; j < 16; ++j) {
    int k = base + j * 256 + t;
    if (k < N_EDGES) atomicAdd(&h[row[k] >> 8], 1);
  }
  __syncthreads();
  for (int i = t; i < NB; i += 256)
    if (h[i]) atomicAdd(&ghist[i], h[i]);
}

// ---- binScan: scan bucket sizes -> bases + cursors; row_start[N] = E
__global__ __launch_bounds__(256) void binScan(const int* __restrict__ ghist,
                                               int* __restrict__ bbase,
                                               int* __restrict__ gcur,
                                               int* __restrict__ row_start) {
  __shared__ int h[NB];
  const int t = threadIdx.x;
  if (t < NB) h[t] = ghist[t];
  __syncthreads();
  if (t == 0) {
    int run = 0;
    for (int i = 0; i < NB; ++i) { int v = h[i]; h[i] = run; run += v; }
  }
  __syncthreads();
  if (t < NB) { bbase[t] = h[t]; gcur[t] = h[t]; }
  if (t == 0) row_start[N_NODES] = N_EDGES;
}

// ---- binA2: group 4096 edges by bucket in LDS, copy out bucket-contiguous
__global__ __launch_bounds__(256) void binA2(const int* __restrict__ row,
                                             const int* __restrict__ col,
                                             int* __restrict__ gcur,
                                             unsigned* __restrict__ gstage) {
  __shared__ int h[NB], lofs[NB], lcur[NB], gb[NB];
  __shared__ unsigned stage[EPB];
  const int t = threadIdx.x;
  for (int i = t; i < NB; i += 256) { h[i] = 0; lcur[i] = 0; }
  __syncthreads();
  const int base = blockIdx.x * EPB;
  const int cnt = min(EPB, N_EDGES - base);
#pragma unroll
  for (int j = 0; j < 16; ++j) {
    int k = base + j * 256 + t;
    if (k < N_EDGES) atomicAdd(&h[row[k] >> 8], 1);
  }
  __syncthreads();
  if (t == 0) {
    int run = 0;
    for (int i = 0; i < NB; ++i) { lofs[i] = run; run += h[i]; }
  }
  __syncthreads();
  if (t < NB && h[t] > 0) gb[t] = atomicAdd(&gcur[t], h[t]);
  __syncthreads();
#pragma unroll
  for (int j = 0; j < 16; ++j) {
    int k = base + j * 256 + t;
    if (k < N_EDGES) {
      int r = row[k], b = r >> 8;
      int lp = lofs[b] + atomicAdd(&lcur[b], 1);
      stage[lp] = ((unsigned)b << 24) | ((unsigned)(r & 255) << 16) |
                  (unsigned)col[k];
    }
  }
  __syncthreads();
#pragma unroll
  for (int j = 0; j < 16; ++j) {
    int s = j * 256 + t;
    if (s < cnt) {
      unsigned wv = stage[s];
      int b = wv >> 24;
      gstage[gb[b] + (s - lofs[b])] = wv & 0x00FFFFFFu;  // (localrow,col)
    }
  }
}

// ---- binB: per-row counts -> row_start; compute exp weight ONCE PER EDGE
// (vs 64x per wave-lane in pull) and pack (exw_fp16<<16 | col) into csr.
__global__ __launch_bounds__(256) void binB(const int* __restrict__ ghist,
                                            const int* __restrict__ bbase,
                                            const unsigned* __restrict__ gstage,
                                            const float* __restrict__ f_dst,
                                            const float* __restrict__ f_row,
                                            int* __restrict__ row_start,
                                            unsigned* __restrict__ csr) {
  __shared__ int cnt[256], cur[256];
  const int t = threadIdx.x;
  const int b = blockIdx.x;
  cnt[t] = 0;
  __syncthreads();
  const int nb = ghist[b], start = bbase[b];
  for (int s = t; s < nb; s += 256) {
    unsigned wv = gstage[start + s];
    atomicAdd(&cnt[(wv >> 16) & 255], 1);
  }
  __syncthreads();
  if (t == 0) {
    int run = 0;
    for (int i = 0; i < 256; ++i) { int v = cnt[i]; cur[i] = run; run += v; }
  }
  __syncthreads();
  const int gr = (b << 8) + t;
  const int myoff = cur[t];
  if (gr < N_NODES) row_start[gr] = start + myoff;
  __syncthreads();
  for (int s = t; s < nb; s += 256) {
    unsigned wv = gstage[start + s];
    int lr = (wv >> 16) & 255;
    int c = wv & 0xFFFF;
    float ev = f_dst[c] + f_row[(b << 8) + lr];
    ev = ev > 0.f ? ev : ALPHA * ev;
    float ex = __expf(ev);
    int p = start + atomicAdd(&cur[lr], 1);
    csr[p] = ((unsigned)f2h_bits(ex) << 16) | (unsigned)c;
  }
}

// ---- pull: 8-deep unrolled gather; weights pre-baked fp16 in csr entries.
__global__ __launch_bounds__(256) void gat_pull(const int* __restrict__ row_start,
                                                const unsigned* __restrict__ csr,
                                                const _Float16* __restrict__ Wh,
                                                float* __restrict__ out) {
  const int lane = threadIdx.x & 63, w = threadIdx.x >> 6;
  const int i = blockIdx.x * 4 + w;
  if (i >= N_NODES) return;
  const int s = row_start[i], e = row_start[i + 1];
  const half4* Wh4 = (const half4*)Wh;
  float4 acc = make_float4(0.f, 0.f, 0.f, 0.f);
  float sum = 0.f;
  if (e > s) {
    for (int p = s; p < e; p += 8) {
      unsigned wv[8];
#pragma unroll
      for (int j = 0; j < 8; ++j) {
        int q = p + j;
        wv[j] = csr[q < e ? q : s];  // clamp: redundant loads hit L1
      }
      half4 v[8];
#pragma unroll
      for (int j = 0; j < 8; ++j)
        v[j] = Wh4[(size_t)(wv[j] & 0xFFFFu) * 64 + lane];
#pragma unroll
      for (int j = 0; j < 8; ++j) {
        float xw = h_bits2f((unsigned short)(wv[j] >> 16));
        xw = (p + j < e) ? xw : 0.f;
        sum += xw;
        acc.x += xw * (float)v[j][0];
        acc.y += xw * (float)v[j][1];
        acc.z += xw * (float)v[j][2];
        acc.w += xw * (float)v[j][3];
      }
    }
    float inv = 1.0f / sum;
    acc.x *= inv; acc.y *= inv; acc.z *= inv; acc.w *= inv;
  }
  acc.x = fmaxf(acc.x, 0.f); acc.y = fmaxf(acc.y, 0.f);
  acc.z = fmaxf(acc.z, 0.f); acc.w = fmaxf(acc.w, 0.f);
  ((float4*)out)[(size_t)i * 64 + lane] = acc;
}

extern "C" void kernel_launch(void* const* d_in, const int* in_sizes, int n_in,
                              void* d_out, int out_size, void* d_ws, size_t ws_size,
                              hipStream_t stream) {
  const float* x   = (const float*)d_in[0];
  const float* W_w = (const float*)d_in[1];
  const float* W_b = (const float*)d_in[2];
  const float* a_w = (const float*)d_in[3];
  const float* a_b = (const float*)d_in[4];
  const int*   row = (const int*)d_in[5];
  const int*   col = (const int*)d_in[6];
  float* out = (float*)d_out;

  float* ws = (float*)d_ws;
  size_t off = 0;
  _Float16* Wh = (_Float16*)(ws + off); off += (size_t)NP * F / 2;       // fp16
  unsigned short* x_bf = (unsigned short*)(ws + off); off += (size_t)NP * F / 2;
  unsigned short* Wt = (unsigned short*)(ws + off); off += (F * F) / 2;  // bf16
  float* wa = ws + off;            off += 2 * F;
  float* cb = ws + off;            off += 8;
  float* f_dst = ws + off;         off += NP;
  float* f_row = ws + off;         off += NP;
  int* ghist = (int*)(ws + off);   off += NB;     // memset 0
  int* bbase = (int*)(ws + off);   off += NB;
  int* gcur = (int*)(ws + off);    off += NB;
  int* row_start = (int*)(ws + off); off += NP;   // N+1 fits
  unsigned* gstage = (unsigned*)(ws + off); off += N_EDGES;
  unsigned* csr = (unsigned*)(ws + off); off += N_EDGES;
  (void)ws_size; (void)in_sizes; (void)n_in; (void)out_size;

  hipMemsetAsync(ghist, 0, NB * sizeof(int), stream);

  hipLaunchKernelGGL(prep_w, dim3(F / 4), dim3(256), 0, stream, W_w, a_w, W_b,
                     a_b, Wt, wa, cb);
  hipLaunchKernelGGL(fvec2, dim3((N_NODES + 3) / 4), dim3(256), 0, stream,
                     x, wa, cb, f_dst, f_row, x_bf);
  hipLaunchKernelGGL(gemm_mfma, dim3(NP / 128, F / 128), dim3(256), 0, stream,
                     x_bf, Wt, W_b, Wh);
  hipLaunchKernelGGL(binA1, dim3(NAB), dim3(256), 0, stream, row, ghist);
  hipLaunchKernelGGL(binScan, dim3(1), dim3(256), 0, stream, ghist, bbase,
                     gcur, row_start);
  hipLaunchKernelGGL(binA2, dim3(NAB), dim3(256), 0, stream, row, col, gcur,
                     gstage);
  hipLaunchKernelGGL(binB, dim3(NB), dim3(256), 0, stream, ghist, bbase,
                     gstage, f_dst, f_row, row_start, csr);
  hipLaunchKernelGGL(gat_pull, dim3((N_NODES + 3) / 4), dim3(256), 0, stream,
                     row_start, csr, Wh, out);
}